// Round 6
// baseline (3750.430 us; speedup 1.0000x reference)
//
#include <hip/hip_runtime.h>
#include <math.h>

#define MROWS 12544        // B*N = 64*196
#define KDIM  768
#define EMB   32
#define NCODE 8192
#define ZQ_ELEMS 401408    // 64*32*14*14

// ---------------------------------------------------------------------------
// K0: normalize codebook rows; also store ||e||^2 (post-normalization, as ref)
// ---------------------------------------------------------------------------
__global__ __launch_bounds__(256) void k0_norm_codebook(
    const float* __restrict__ cb, float* __restrict__ em, float* __restrict__ n2)
{
    const int t = threadIdx.x;
    const int c = t & 31;
    const int r = blockIdx.x * 8 + (t >> 5);
    float v = cb[r * 32 + c];
    float s = v * v;
    #pragma unroll
    for (int off = 16; off; off >>= 1) s += __shfl_xor(s, off, 32);
    float e = v / sqrtf(s + 1e-12f);
    em[r * 32 + c] = e;
    float s2 = e * e;
    #pragma unroll
    for (int off = 16; off; off >>= 1) s2 += __shfl_xor(s2, off, 32);
    if (c == 0) n2[r] = s2;
}

// ---------------------------------------------------------------------------
// K1: H = tanh(X @ W1^T + b1).  64x192 tile, BK=16, 256 threads, 4x12 microtile.
// Grid (196, 4) = 784 blocks <= 1024 resident (4 blocks/CU @ VGPR<=128) ->
// single dispatch round (R4's 1176-block grid ran 2 rounds, 2nd 13% full).
// Register staging (R5's global_load_lds forced uncoalesced column reads:
// 638us). LDS 33KB. Bank patterns 2-way (free).
// ---------------------------------------------------------------------------
#define BM1 64
#define BN1 192
#define BK1 16

__global__ __launch_bounds__(256, 4) void k1_gemm_tanh(
    const float* __restrict__ A, const float* __restrict__ W,
    const float* __restrict__ bias, float* __restrict__ H)
{
    __shared__ __align__(16) float As[2][BK1][68];
    __shared__ __align__(16) float Bs[2][BK1][196];

    const int t    = threadIdx.x;
    const int row0 = blockIdx.x * BM1;
    const int col0 = blockIdx.y * BN1;
    const int tc   = t & 15;          // cols tc*4 + {0,64,128}
    const int tr   = t >> 4;          // rows tr*4..+3

    const int am = t >> 2, ak = (t & 3) * 4;   // stage: row am, k ak..ak+3

    const float* Ap = A + (size_t)(row0 + am) * KDIM + ak;
    const float* Bp = W + (size_t)(col0 + am) * KDIM + ak;  // rows am, am+64, am+128

    float acc[4][12];
    #pragma unroll
    for (int i = 0; i < 4; ++i)
        #pragma unroll
        for (int j = 0; j < 12; ++j) acc[i][j] = 0.f;

    // preload tile 0 (transposed into LDS)
    {
        float4 a  = *(const float4*)(Ap);
        float4 b0 = *(const float4*)(Bp);
        float4 b1 = *(const float4*)(Bp + (size_t)64 * KDIM);
        float4 b2 = *(const float4*)(Bp + (size_t)128 * KDIM);
        As[0][ak+0][am] = a.x;  As[0][ak+1][am] = a.y;  As[0][ak+2][am] = a.z;  As[0][ak+3][am] = a.w;
        Bs[0][ak+0][am] = b0.x; Bs[0][ak+1][am] = b0.y; Bs[0][ak+2][am] = b0.z; Bs[0][ak+3][am] = b0.w;
        Bs[0][ak+0][am+64] = b1.x; Bs[0][ak+1][am+64] = b1.y; Bs[0][ak+2][am+64] = b1.z; Bs[0][ak+3][am+64] = b1.w;
        Bs[0][ak+0][am+128] = b2.x; Bs[0][ak+1][am+128] = b2.y; Bs[0][ak+2][am+128] = b2.z; Bs[0][ak+3][am+128] = b2.w;
    }
    __syncthreads();

    const int nkt = KDIM / BK1;   // 48
    int buf = 0;
    for (int kt = 0; kt < nkt; ++kt) {
        float4 na, nb0, nb1, nb2;
        const bool pf = (kt + 1 < nkt);
        if (pf) {
            const int ko = (kt + 1) * BK1;
            na  = *(const float4*)(Ap + ko);
            nb0 = *(const float4*)(Bp + ko);
            nb1 = *(const float4*)(Bp + (size_t)64 * KDIM + ko);
            nb2 = *(const float4*)(Bp + (size_t)128 * KDIM + ko);
        }
        #pragma unroll
        for (int k = 0; k < BK1; ++k) {
            float4 av  = *(const float4*)&As[buf][k][tr * 4];
            float4 bv0 = *(const float4*)&Bs[buf][k][tc * 4];
            float4 bv1 = *(const float4*)&Bs[buf][k][tc * 4 + 64];
            float4 bv2 = *(const float4*)&Bs[buf][k][tc * 4 + 128];
            float a_[4]  = {av.x, av.y, av.z, av.w};
            float b_[12] = {bv0.x, bv0.y, bv0.z, bv0.w,
                            bv1.x, bv1.y, bv1.z, bv1.w,
                            bv2.x, bv2.y, bv2.z, bv2.w};
            #pragma unroll
            for (int i = 0; i < 4; ++i)
                #pragma unroll
                for (int j = 0; j < 12; ++j)
                    acc[i][j] = fmaf(a_[i], b_[j], acc[i][j]);
        }
        if (pf) {
            const int nb = buf ^ 1;
            As[nb][ak+0][am] = na.x;  As[nb][ak+1][am] = na.y;  As[nb][ak+2][am] = na.z;  As[nb][ak+3][am] = na.w;
            Bs[nb][ak+0][am] = nb0.x; Bs[nb][ak+1][am] = nb0.y; Bs[nb][ak+2][am] = nb0.z; Bs[nb][ak+3][am] = nb0.w;
            Bs[nb][ak+0][am+64] = nb1.x; Bs[nb][ak+1][am+64] = nb1.y; Bs[nb][ak+2][am+64] = nb1.z; Bs[nb][ak+3][am+64] = nb1.w;
            Bs[nb][ak+0][am+128] = nb2.x; Bs[nb][ak+1][am+128] = nb2.y; Bs[nb][ak+2][am+128] = nb2.z; Bs[nb][ak+3][am+128] = nb2.w;
        }
        __syncthreads();
        buf ^= 1;
    }

    float4 bc0 = *(const float4*)&bias[col0 + tc * 4];
    float4 bc1 = *(const float4*)&bias[col0 + 64 + tc * 4];
    float4 bc2 = *(const float4*)&bias[col0 + 128 + tc * 4];
    #pragma unroll
    for (int i = 0; i < 4; ++i) {
        const int row = row0 + tr * 4 + i;
        float o0 = tanhf(acc[i][0] + bc0.x);
        float o1 = tanhf(acc[i][1] + bc0.y);
        float o2 = tanhf(acc[i][2] + bc0.z);
        float o3 = tanhf(acc[i][3] + bc0.w);
        float o4 = tanhf(acc[i][4] + bc1.x);
        float o5 = tanhf(acc[i][5] + bc1.y);
        float o6 = tanhf(acc[i][6] + bc1.z);
        float o7 = tanhf(acc[i][7] + bc1.w);
        float o8 = tanhf(acc[i][8] + bc2.x);
        float o9 = tanhf(acc[i][9] + bc2.y);
        float o10 = tanhf(acc[i][10] + bc2.z);
        float o11 = tanhf(acc[i][11] + bc2.w);
        *(float4*)&H[(size_t)row * KDIM + col0 + tc * 4]       = make_float4(o0, o1, o2, o3);
        *(float4*)&H[(size_t)row * KDIM + col0 + 64 + tc * 4]  = make_float4(o4, o5, o6, o7);
        *(float4*)&H[(size_t)row * KDIM + col0 + 128 + tc * 4] = make_float4(o8, o9, o10, o11);
    }
}

// ---------------------------------------------------------------------------
// K2: Z = l2norm(H @ W2^T + b2).  32 rows/block -> 392 blocks.
// ---------------------------------------------------------------------------
#define K2C 64
__global__ __launch_bounds__(256) void k2_gemm_norm(
    const float* __restrict__ H, const float* __restrict__ W2,
    const float* __restrict__ b2, float* __restrict__ Z)
{
    __shared__ __align__(16) float As2[32][68];
    __shared__ __align__(16) float Ws2[32][68];

    const int t    = threadIdx.x;
    const int row0 = blockIdx.x * 32;
    const int cg   = t & 7;
    const int rg   = t >> 3;

    float acc[4] = {0.f, 0.f, 0.f, 0.f};

    for (int kc = 0; kc < KDIM; kc += K2C) {
        __syncthreads();
        {
            const int r = t >> 3, kq = (t & 7) * 8;
            *(float4*)&As2[r][kq]     = *(const float4*)&H[(size_t)(row0 + r) * KDIM + kc + kq];
            *(float4*)&As2[r][kq + 4] = *(const float4*)&H[(size_t)(row0 + r) * KDIM + kc + kq + 4];
            *(float4*)&Ws2[r][kq]     = *(const float4*)&W2[(size_t)r * KDIM + kc + kq];
            *(float4*)&Ws2[r][kq + 4] = *(const float4*)&W2[(size_t)r * KDIM + kc + kq + 4];
        }
        __syncthreads();
        #pragma unroll
        for (int k4 = 0; k4 < K2C / 4; ++k4) {
            float4 a4 = *(const float4*)&As2[rg][k4 * 4];
            #pragma unroll
            for (int c = 0; c < 4; ++c) {
                float4 w4 = *(const float4*)&Ws2[cg * 4 + c][k4 * 4];
                acc[c] = fmaf(a4.x, w4.x, acc[c]);
                acc[c] = fmaf(a4.y, w4.y, acc[c]);
                acc[c] = fmaf(a4.z, w4.z, acc[c]);
                acc[c] = fmaf(a4.w, w4.w, acc[c]);
            }
        }
    }

    float h0 = acc[0] + b2[cg * 4 + 0];
    float h1 = acc[1] + b2[cg * 4 + 1];
    float h2 = acc[2] + b2[cg * 4 + 2];
    float h3 = acc[3] + b2[cg * 4 + 3];
    float s = h0*h0 + h1*h1 + h2*h2 + h3*h3;
    #pragma unroll
    for (int off = 1; off < 8; off <<= 1) s += __shfl_xor(s, off, 8);
    const float den = sqrtf(s + 1e-12f);
    const int r = row0 + rg;
    *(float4*)&Z[(size_t)r * EMB + cg * 4] = make_float4(h0/den, h1/den, h2/den, h3/den);
}

// ---------------------------------------------------------------------------
// K3: per (64-row block, 2048-code split) partial argmin of ||e||^2 - 2 z.e
// Grid (196, 4) = 784 blocks. Single-buffered staging. LDS 27.5KB.
// ---------------------------------------------------------------------------
__global__ __launch_bounds__(256) void k3_argmin_part(
    const float* __restrict__ Z, const float* __restrict__ EM,
    const float* __restrict__ N2, float* __restrict__ pminv,
    float* __restrict__ pmini)
{
    __shared__ __align__(16) float Zs[64][36];
    __shared__ __align__(16) float Es[128][36];
    __shared__ float Ns[128];

    const int t     = threadIdx.x;
    const int row0  = blockIdx.x * 64;
    const int cbase = blockIdx.y * 2048;
    const int cg    = t & 15;
    const int rg    = t >> 4;

    #pragma unroll
    for (int i = 0; i < 2; ++i) {
        const int fi = t + 256 * i;
        const int r = fi >> 3, kq = fi & 7;
        *(float4*)&Zs[r][kq * 4] = *(const float4*)&Z[(size_t)(row0 + r) * EMB + kq * 4];
    }

    float minv[4] = {INFINITY, INFINITY, INFINITY, INFINITY};
    int   mini[4] = {0, 0, 0, 0};

    for (int tile = 0; tile < 16; ++tile) {
        __syncthreads();
        const int tb = cbase + tile * 128;
        #pragma unroll
        for (int i = 0; i < 4; ++i) {
            const int fi = t + 256 * i;
            const int c = fi >> 3, kq = fi & 7;
            *(float4*)&Es[c][kq * 4] = *(const float4*)&EM[(size_t)(tb + c) * EMB + kq * 4];
        }
        if (t < 128) Ns[t] = N2[tb + t];
        __syncthreads();

        float dot[4][8];
        #pragma unroll
        for (int rr = 0; rr < 4; ++rr)
            #pragma unroll
            for (int cc = 0; cc < 8; ++cc) dot[rr][cc] = 0.f;

        #pragma unroll
        for (int k4 = 0; k4 < 8; ++k4) {
            float4 z4[4];
            #pragma unroll
            for (int rr = 0; rr < 4; ++rr) z4[rr] = *(const float4*)&Zs[rg + 16 * rr][k4 * 4];
            #pragma unroll
            for (int cc = 0; cc < 8; ++cc) {
                float4 e4 = *(const float4*)&Es[cg + 16 * cc][k4 * 4];
                #pragma unroll
                for (int rr = 0; rr < 4; ++rr) {
                    dot[rr][cc] = fmaf(z4[rr].x, e4.x, dot[rr][cc]);
                    dot[rr][cc] = fmaf(z4[rr].y, e4.y, dot[rr][cc]);
                    dot[rr][cc] = fmaf(z4[rr].z, e4.z, dot[rr][cc]);
                    dot[rr][cc] = fmaf(z4[rr].w, e4.w, dot[rr][cc]);
                }
            }
        }
        #pragma unroll
        for (int cc = 0; cc < 8; ++cc) {
            const int cl = cg + 16 * cc;
            const float n2v = Ns[cl];
            const int gi = tb + cl;
            #pragma unroll
            for (int rr = 0; rr < 4; ++rr) {
                const float sc = fmaf(-2.f, dot[rr][cc], n2v);
                if (sc < minv[rr]) { minv[rr] = sc; mini[rr] = gi; }
            }
        }
    }

    // reduce across 16 code-group lanes per row; ties -> smaller index
    #pragma unroll
    for (int rr = 0; rr < 4; ++rr) {
        #pragma unroll
        for (int off = 8; off; off >>= 1) {
            const float ov = __shfl_xor(minv[rr], off, 16);
            const int   oi = __shfl_xor(mini[rr], off, 16);
            if (ov < minv[rr] || (ov == minv[rr] && oi < mini[rr])) {
                minv[rr] = ov; mini[rr] = oi;
            }
        }
        if (cg == 0) {
            const int row = row0 + rg + 16 * rr;
            pminv[row * 4 + blockIdx.y] = minv[rr];
            pmini[row * 4 + blockIdx.y] = (float)mini[rr];
        }
    }
}

// ---------------------------------------------------------------------------
// K3b: merge 4 splits per row; write token, z_q (B,32,14,14), loss partials.
// ---------------------------------------------------------------------------
__global__ __launch_bounds__(256) void k3b_merge(
    const float* __restrict__ Z, const float* __restrict__ EM,
    const float* __restrict__ pminv, const float* __restrict__ pmini,
    float* __restrict__ tok, float* __restrict__ zq, float* __restrict__ part)
{
    const int t = threadIdx.x;
    const int row = blockIdx.x * 256 + t;

    float4 mv = *(const float4*)&pminv[row * 4];
    float4 mi = *(const float4*)&pmini[row * 4];
    float best = mv.x; int bi = (int)mi.x;
    if (mv.y < best) { best = mv.y; bi = (int)mi.y; }
    if (mv.z < best) { best = mv.z; bi = (int)mi.z; }
    if (mv.w < best) { best = mv.w; bi = (int)mi.w; }
    tok[row] = (float)bi;

    const int b = row / 196, n = row % 196;
    float lp = 0.f;
    #pragma unroll
    for (int q = 0; q < 8; ++q) {
        float4 e = *(const float4*)&EM[(size_t)bi * EMB + q * 4];
        float4 z = *(const float4*)&Z[(size_t)row * EMB + q * 4];
        float d0 = e.x - z.x, d1 = e.y - z.y, d2 = e.z - z.z, d3 = e.w - z.w;
        lp = fmaf(d0, d0, lp); lp = fmaf(d1, d1, lp);
        lp = fmaf(d2, d2, lp); lp = fmaf(d3, d3, lp);
        const size_t zb = (size_t)b * 6272 + n;
        zq[zb + (q * 4 + 0) * 196] = e.x;
        zq[zb + (q * 4 + 1) * 196] = e.y;
        zq[zb + (q * 4 + 2) * 196] = e.z;
        zq[zb + (q * 4 + 3) * 196] = e.w;
    }
    #pragma unroll
    for (int off = 32; off; off >>= 1) lp += __shfl_xor(lp, off, 64);
    __shared__ float r4[4];
    if ((t & 63) == 0) r4[t >> 6] = lp;
    __syncthreads();
    if (t == 0) part[blockIdx.x] = r4[0] + r4[1] + r4[2] + r4[3];
}

// ---------------------------------------------------------------------------
// K4: deterministic loss reduce over 49 partials
// ---------------------------------------------------------------------------
__global__ __launch_bounds__(64) void k4_loss(
    const float* __restrict__ part, float* __restrict__ loss)
{
    const int t = threadIdx.x;
    float v = (t < 49) ? part[t] : 0.f;
    #pragma unroll
    for (int off = 32; off; off >>= 1) v += __shfl_xor(v, off, 64);
    if (t == 0) loss[0] = v * (1.0f / 401408.f);
}

// ---------------------------------------------------------------------------
extern "C" void kernel_launch(void* const* d_in, const int* in_sizes, int n_in,
                              void* d_out, int out_size, void* d_ws, size_t ws_size,
                              hipStream_t stream)
{
    (void)in_sizes; (void)n_in; (void)out_size; (void)ws_size;
    const float* features = (const float*)d_in[0];
    const float* w1 = (const float*)d_in[1];
    const float* b1 = (const float*)d_in[2];
    const float* w2 = (const float*)d_in[3];
    const float* b2 = (const float*)d_in[4];
    const float* cb = (const float*)d_in[5];

    float* out  = (float*)d_out;
    float* tok  = out;                       // 12544
    float* zq   = out + MROWS;               // 401408
    float* loss = out + MROWS + ZQ_ELEMS;    // 1

    float* ws   = (float*)d_ws;
    float* H    = ws;                         // 12544*768
    float* Zb   = H + (size_t)MROWS * KDIM;   // 12544*32
    float* EM   = Zb + (size_t)MROWS * EMB;   // 8192*32
    float* N2   = EM + (size_t)NCODE * EMB;   // 8192
    float* PART = N2 + NCODE;                 // 64
    // H is dead after K2 -> reuse its space for the per-split argmin pairs
    float* PMINV = H;                         // 12544*4
    float* PMINI = H + (size_t)MROWS * 4;     // 12544*4

    k0_norm_codebook<<<NCODE / 8, 256, 0, stream>>>(cb, EM, N2);
    k1_gemm_tanh<<<dim3(MROWS / BM1, KDIM / BN1), 256, 0, stream>>>(features, w1, b1, H);
    k2_gemm_norm<<<MROWS / 32, 256, 0, stream>>>(H, w2, b2, Zb);
    k3_argmin_part<<<dim3(MROWS / 64, 4), 256, 0, stream>>>(Zb, EM, N2, PMINV, PMINI);
    k3b_merge<<<MROWS / 256, 256, 0, stream>>>(Zb, EM, PMINV, PMINI, tok, zq, PART);
    k4_loss<<<1, 64, 0, stream>>>(PART, loss);
}

// Round 7
// 2463.341 us; speedup vs baseline: 1.5225x; 1.5225x over previous
//
#include <hip/hip_runtime.h>
#include <math.h>

#define MROWS 12544        // B*N = 64*196
#define KDIM  768
#define EMB   32
#define NCODE 8192
#define ZQ_ELEMS 401408    // 64*32*14*14

// ---------------------------------------------------------------------------
// K0: normalize codebook rows; also store ||e||^2 (post-normalization, as ref)
// ---------------------------------------------------------------------------
__global__ __launch_bounds__(256) void k0_norm_codebook(
    const float* __restrict__ cb, float* __restrict__ em, float* __restrict__ n2)
{
    const int t = threadIdx.x;
    const int c = t & 31;
    const int r = blockIdx.x * 8 + (t >> 5);
    float v = cb[r * 32 + c];
    float s = v * v;
    #pragma unroll
    for (int off = 16; off; off >>= 1) s += __shfl_xor(s, off, 32);
    float e = v / sqrtf(s + 1e-12f);
    em[r * 32 + c] = e;
    float s2 = e * e;
    #pragma unroll
    for (int off = 16; off; off >>= 1) s2 += __shfl_xor(s2, off, 32);
    if (c == 0) n2[r] = s2;
}

// ---------------------------------------------------------------------------
// K1: H = tanh(X @ W1^T + b1).  64x128 tile, BK=16, **128 threads**, 8x8
// microtile with STRIDED fragments.
//  - LDS-ratio theory (R4: VALUBusy 62% = LDS-instr-bound): 64 FMA per
//    4 ds_read_b128 = 16:1 (was 10.7:1) -> VALU/LDS near-balanced.
//  - Strided frags: rows {tr*4, 32+tr*4}, cols {tc*4, 64+tc*4} -> every
//    b128 read <=2-way (free). R1's contiguous-8 frags were 4-way.
//  - NO second __launch_bounds__ arg: (256,4) forced VGPR=64 + GB-scale
//    spill twice (R3, R6). Let compiler pick (~160-200 -> 2 waves/SIMD,
//    4 blocks/CU, grid 1176 -> ~9% tail).
// ---------------------------------------------------------------------------
#define BM1 64
#define BN1 128
#define BK1 16

__global__ void k1_gemm_tanh(
    const float* __restrict__ A, const float* __restrict__ W,
    const float* __restrict__ bias, float* __restrict__ H)
{
    __shared__ __align__(16) float As[2][BK1][64];
    __shared__ __align__(16) float Bs[2][BK1][128];

    const int t    = threadIdx.x;      // 0..127
    const int row0 = blockIdx.x * BM1;
    const int col0 = blockIdx.y * BN1;
    const int tc   = t & 15;           // cols tc*4+{0..3} and 64+tc*4+{0..3}
    const int tr   = t >> 4;           // 0..7: rows tr*4+{0..3} and 32+tr*4+{0..3}

    const int arow = t & 63;           // A stage: row arow, k akq..akq+7
    const int akq  = (t >> 6) * 8;
    const int bcol = t;                // B stage: col bcol, k 0..15

    const float* Ap = A + (size_t)(row0 + arow) * KDIM + akq;
    const float* Bp = W + (size_t)(col0 + bcol) * KDIM;

    float acc[8][8];
    #pragma unroll
    for (int i = 0; i < 8; ++i)
        #pragma unroll
        for (int j = 0; j < 8; ++j) acc[i][j] = 0.f;

    // preload tile 0 (transposed into LDS; writes are 2-way = free)
    {
        float4 a0 = *(const float4*)(Ap);
        float4 a1 = *(const float4*)(Ap + 4);
        float4 b0 = *(const float4*)(Bp);
        float4 b1 = *(const float4*)(Bp + 4);
        float4 b2 = *(const float4*)(Bp + 8);
        float4 b3 = *(const float4*)(Bp + 12);
        As[0][akq+0][arow] = a0.x; As[0][akq+1][arow] = a0.y; As[0][akq+2][arow] = a0.z; As[0][akq+3][arow] = a0.w;
        As[0][akq+4][arow] = a1.x; As[0][akq+5][arow] = a1.y; As[0][akq+6][arow] = a1.z; As[0][akq+7][arow] = a1.w;
        Bs[0][0][bcol] = b0.x;  Bs[0][1][bcol] = b0.y;  Bs[0][2][bcol] = b0.z;  Bs[0][3][bcol] = b0.w;
        Bs[0][4][bcol] = b1.x;  Bs[0][5][bcol] = b1.y;  Bs[0][6][bcol] = b1.z;  Bs[0][7][bcol] = b1.w;
        Bs[0][8][bcol] = b2.x;  Bs[0][9][bcol] = b2.y;  Bs[0][10][bcol] = b2.z; Bs[0][11][bcol] = b2.w;
        Bs[0][12][bcol] = b3.x; Bs[0][13][bcol] = b3.y; Bs[0][14][bcol] = b3.z; Bs[0][15][bcol] = b3.w;
    }
    __syncthreads();

    const int nkt = KDIM / BK1;   // 48
    int buf = 0;
    for (int kt = 0; kt < nkt; ++kt) {
        float4 na0, na1, nb0, nb1, nb2, nb3;
        const bool pf = (kt + 1 < nkt);
        if (pf) {
            const int ko = (kt + 1) * BK1;
            na0 = *(const float4*)(Ap + ko);
            na1 = *(const float4*)(Ap + ko + 4);
            nb0 = *(const float4*)(Bp + ko);
            nb1 = *(const float4*)(Bp + ko + 4);
            nb2 = *(const float4*)(Bp + ko + 8);
            nb3 = *(const float4*)(Bp + ko + 12);
        }
        #pragma unroll
        for (int k = 0; k < BK1; ++k) {
            float4 a0 = *(const float4*)&As[buf][k][tr * 4];
            float4 a1 = *(const float4*)&As[buf][k][32 + tr * 4];
            float4 b0 = *(const float4*)&Bs[buf][k][tc * 4];
            float4 b1 = *(const float4*)&Bs[buf][k][64 + tc * 4];
            float a_[8] = {a0.x, a0.y, a0.z, a0.w, a1.x, a1.y, a1.z, a1.w};
            float b_[8] = {b0.x, b0.y, b0.z, b0.w, b1.x, b1.y, b1.z, b1.w};
            #pragma unroll
            for (int i = 0; i < 8; ++i)
                #pragma unroll
                for (int j = 0; j < 8; ++j)
                    acc[i][j] = fmaf(a_[i], b_[j], acc[i][j]);
        }
        if (pf) {
            const int nb = buf ^ 1;
            As[nb][akq+0][arow] = na0.x; As[nb][akq+1][arow] = na0.y; As[nb][akq+2][arow] = na0.z; As[nb][akq+3][arow] = na0.w;
            As[nb][akq+4][arow] = na1.x; As[nb][akq+5][arow] = na1.y; As[nb][akq+6][arow] = na1.z; As[nb][akq+7][arow] = na1.w;
            Bs[nb][0][bcol] = nb0.x;  Bs[nb][1][bcol] = nb0.y;  Bs[nb][2][bcol] = nb0.z;  Bs[nb][3][bcol] = nb0.w;
            Bs[nb][4][bcol] = nb1.x;  Bs[nb][5][bcol] = nb1.y;  Bs[nb][6][bcol] = nb1.z;  Bs[nb][7][bcol] = nb1.w;
            Bs[nb][8][bcol] = nb2.x;  Bs[nb][9][bcol] = nb2.y;  Bs[nb][10][bcol] = nb2.z; Bs[nb][11][bcol] = nb2.w;
            Bs[nb][12][bcol] = nb3.x; Bs[nb][13][bcol] = nb3.y; Bs[nb][14][bcol] = nb3.z; Bs[nb][15][bcol] = nb3.w;
        }
        __syncthreads();
        buf ^= 1;
    }

    float4 bc0 = *(const float4*)&bias[col0 + tc * 4];
    float4 bc1 = *(const float4*)&bias[col0 + 64 + tc * 4];
    #pragma unroll
    for (int i = 0; i < 8; ++i) {
        const int row = row0 + ((i < 4) ? (tr * 4 + i) : (32 + tr * 4 + i - 4));
        float o0 = tanhf(acc[i][0] + bc0.x);
        float o1 = tanhf(acc[i][1] + bc0.y);
        float o2 = tanhf(acc[i][2] + bc0.z);
        float o3 = tanhf(acc[i][3] + bc0.w);
        float o4 = tanhf(acc[i][4] + bc1.x);
        float o5 = tanhf(acc[i][5] + bc1.y);
        float o6 = tanhf(acc[i][6] + bc1.z);
        float o7 = tanhf(acc[i][7] + bc1.w);
        *(float4*)&H[(size_t)row * KDIM + col0 + tc * 4]      = make_float4(o0, o1, o2, o3);
        *(float4*)&H[(size_t)row * KDIM + col0 + 64 + tc * 4] = make_float4(o4, o5, o6, o7);
    }
}

// ---------------------------------------------------------------------------
// K2: Z = l2norm(H @ W2^T + b2).  32 rows/block -> 392 blocks.
// ---------------------------------------------------------------------------
#define K2C 64
__global__ __launch_bounds__(256) void k2_gemm_norm(
    const float* __restrict__ H, const float* __restrict__ W2,
    const float* __restrict__ b2, float* __restrict__ Z)
{
    __shared__ __align__(16) float As2[32][68];
    __shared__ __align__(16) float Ws2[32][68];

    const int t    = threadIdx.x;
    const int row0 = blockIdx.x * 32;
    const int cg   = t & 7;
    const int rg   = t >> 3;

    float acc[4] = {0.f, 0.f, 0.f, 0.f};

    for (int kc = 0; kc < KDIM; kc += K2C) {
        __syncthreads();
        {
            const int r = t >> 3, kq = (t & 7) * 8;
            *(float4*)&As2[r][kq]     = *(const float4*)&H[(size_t)(row0 + r) * KDIM + kc + kq];
            *(float4*)&As2[r][kq + 4] = *(const float4*)&H[(size_t)(row0 + r) * KDIM + kc + kq + 4];
            *(float4*)&Ws2[r][kq]     = *(const float4*)&W2[(size_t)r * KDIM + kc + kq];
            *(float4*)&Ws2[r][kq + 4] = *(const float4*)&W2[(size_t)r * KDIM + kc + kq + 4];
        }
        __syncthreads();
        #pragma unroll
        for (int k4 = 0; k4 < K2C / 4; ++k4) {
            float4 a4 = *(const float4*)&As2[rg][k4 * 4];
            #pragma unroll
            for (int c = 0; c < 4; ++c) {
                float4 w4 = *(const float4*)&Ws2[cg * 4 + c][k4 * 4];
                acc[c] = fmaf(a4.x, w4.x, acc[c]);
                acc[c] = fmaf(a4.y, w4.y, acc[c]);
                acc[c] = fmaf(a4.z, w4.z, acc[c]);
                acc[c] = fmaf(a4.w, w4.w, acc[c]);
            }
        }
    }

    float h0 = acc[0] + b2[cg * 4 + 0];
    float h1 = acc[1] + b2[cg * 4 + 1];
    float h2 = acc[2] + b2[cg * 4 + 2];
    float h3 = acc[3] + b2[cg * 4 + 3];
    float s = h0*h0 + h1*h1 + h2*h2 + h3*h3;
    #pragma unroll
    for (int off = 1; off < 8; off <<= 1) s += __shfl_xor(s, off, 8);
    const float den = sqrtf(s + 1e-12f);
    const int r = row0 + rg;
    *(float4*)&Z[(size_t)r * EMB + cg * 4] = make_float4(h0/den, h1/den, h2/den, h3/den);
}

// ---------------------------------------------------------------------------
// K3: per (64-row block, 2048-code split) partial argmin of ||e||^2 - 2 z.e
// Grid (196, 4) = 784 blocks. Single-buffered staging. LDS 27.5KB.
// ---------------------------------------------------------------------------
__global__ __launch_bounds__(256) void k3_argmin_part(
    const float* __restrict__ Z, const float* __restrict__ EM,
    const float* __restrict__ N2, float* __restrict__ pminv,
    float* __restrict__ pmini)
{
    __shared__ __align__(16) float Zs[64][36];
    __shared__ __align__(16) float Es[128][36];
    __shared__ float Ns[128];

    const int t     = threadIdx.x;
    const int row0  = blockIdx.x * 64;
    const int cbase = blockIdx.y * 2048;
    const int cg    = t & 15;
    const int rg    = t >> 4;

    #pragma unroll
    for (int i = 0; i < 2; ++i) {
        const int fi = t + 256 * i;
        const int r = fi >> 3, kq = fi & 7;
        *(float4*)&Zs[r][kq * 4] = *(const float4*)&Z[(size_t)(row0 + r) * EMB + kq * 4];
    }

    float minv[4] = {INFINITY, INFINITY, INFINITY, INFINITY};
    int   mini[4] = {0, 0, 0, 0};

    for (int tile = 0; tile < 16; ++tile) {
        __syncthreads();
        const int tb = cbase + tile * 128;
        #pragma unroll
        for (int i = 0; i < 4; ++i) {
            const int fi = t + 256 * i;
            const int c = fi >> 3, kq = fi & 7;
            *(float4*)&Es[c][kq * 4] = *(const float4*)&EM[(size_t)(tb + c) * EMB + kq * 4];
        }
        if (t < 128) Ns[t] = N2[tb + t];
        __syncthreads();

        float dot[4][8];
        #pragma unroll
        for (int rr = 0; rr < 4; ++rr)
            #pragma unroll
            for (int cc = 0; cc < 8; ++cc) dot[rr][cc] = 0.f;

        #pragma unroll
        for (int k4 = 0; k4 < 8; ++k4) {
            float4 z4[4];
            #pragma unroll
            for (int rr = 0; rr < 4; ++rr) z4[rr] = *(const float4*)&Zs[rg + 16 * rr][k4 * 4];
            #pragma unroll
            for (int cc = 0; cc < 8; ++cc) {
                float4 e4 = *(const float4*)&Es[cg + 16 * cc][k4 * 4];
                #pragma unroll
                for (int rr = 0; rr < 4; ++rr) {
                    dot[rr][cc] = fmaf(z4[rr].x, e4.x, dot[rr][cc]);
                    dot[rr][cc] = fmaf(z4[rr].y, e4.y, dot[rr][cc]);
                    dot[rr][cc] = fmaf(z4[rr].z, e4.z, dot[rr][cc]);
                    dot[rr][cc] = fmaf(z4[rr].w, e4.w, dot[rr][cc]);
                }
            }
        }
        #pragma unroll
        for (int cc = 0; cc < 8; ++cc) {
            const int cl = cg + 16 * cc;
            const float n2v = Ns[cl];
            const int gi = tb + cl;
            #pragma unroll
            for (int rr = 0; rr < 4; ++rr) {
                const float sc = fmaf(-2.f, dot[rr][cc], n2v);
                if (sc < minv[rr]) { minv[rr] = sc; mini[rr] = gi; }
            }
        }
    }

    // reduce across 16 code-group lanes per row; ties -> smaller index
    #pragma unroll
    for (int rr = 0; rr < 4; ++rr) {
        #pragma unroll
        for (int off = 8; off; off >>= 1) {
            const float ov = __shfl_xor(minv[rr], off, 16);
            const int   oi = __shfl_xor(mini[rr], off, 16);
            if (ov < minv[rr] || (ov == minv[rr] && oi < mini[rr])) {
                minv[rr] = ov; mini[rr] = oi;
            }
        }
        if (cg == 0) {
            const int row = row0 + rg + 16 * rr;
            pminv[row * 4 + blockIdx.y] = minv[rr];
            pmini[row * 4 + blockIdx.y] = (float)mini[rr];
        }
    }
}

// ---------------------------------------------------------------------------
// K3b: merge 4 splits per row; write token, z_q (B,32,14,14), loss partials.
// ---------------------------------------------------------------------------
__global__ __launch_bounds__(256) void k3b_merge(
    const float* __restrict__ Z, const float* __restrict__ EM,
    const float* __restrict__ pminv, const float* __restrict__ pmini,
    float* __restrict__ tok, float* __restrict__ zq, float* __restrict__ part)
{
    const int t = threadIdx.x;
    const int row = blockIdx.x * 256 + t;

    float4 mv = *(const float4*)&pminv[row * 4];
    float4 mi = *(const float4*)&pmini[row * 4];
    float best = mv.x; int bi = (int)mi.x;
    if (mv.y < best) { best = mv.y; bi = (int)mi.y; }
    if (mv.z < best) { best = mv.z; bi = (int)mi.z; }
    if (mv.w < best) { best = mv.w; bi = (int)mi.w; }
    tok[row] = (float)bi;

    const int b = row / 196, n = row % 196;
    float lp = 0.f;
    #pragma unroll
    for (int q = 0; q < 8; ++q) {
        float4 e = *(const float4*)&EM[(size_t)bi * EMB + q * 4];
        float4 z = *(const float4*)&Z[(size_t)row * EMB + q * 4];
        float d0 = e.x - z.x, d1 = e.y - z.y, d2 = e.z - z.z, d3 = e.w - z.w;
        lp = fmaf(d0, d0, lp); lp = fmaf(d1, d1, lp);
        lp = fmaf(d2, d2, lp); lp = fmaf(d3, d3, lp);
        const size_t zb = (size_t)b * 6272 + n;
        zq[zb + (q * 4 + 0) * 196] = e.x;
        zq[zb + (q * 4 + 1) * 196] = e.y;
        zq[zb + (q * 4 + 2) * 196] = e.z;
        zq[zb + (q * 4 + 3) * 196] = e.w;
    }
    #pragma unroll
    for (int off = 32; off; off >>= 1) lp += __shfl_xor(lp, off, 64);
    __shared__ float r4[4];
    if ((t & 63) == 0) r4[t >> 6] = lp;
    __syncthreads();
    if (t == 0) part[blockIdx.x] = r4[0] + r4[1] + r4[2] + r4[3];
}

// ---------------------------------------------------------------------------
// K4: deterministic loss reduce over 49 partials
// ---------------------------------------------------------------------------
__global__ __launch_bounds__(64) void k4_loss(
    const float* __restrict__ part, float* __restrict__ loss)
{
    const int t = threadIdx.x;
    float v = (t < 49) ? part[t] : 0.f;
    #pragma unroll
    for (int off = 32; off; off >>= 1) v += __shfl_xor(v, off, 64);
    if (t == 0) loss[0] = v * (1.0f / 401408.f);
}

// ---------------------------------------------------------------------------
extern "C" void kernel_launch(void* const* d_in, const int* in_sizes, int n_in,
                              void* d_out, int out_size, void* d_ws, size_t ws_size,
                              hipStream_t stream)
{
    (void)in_sizes; (void)n_in; (void)out_size; (void)ws_size;
    const float* features = (const float*)d_in[0];
    const float* w1 = (const float*)d_in[1];
    const float* b1 = (const float*)d_in[2];
    const float* w2 = (const float*)d_in[3];
    const float* b2 = (const float*)d_in[4];
    const float* cb = (const float*)d_in[5];

    float* out  = (float*)d_out;
    float* tok  = out;                       // 12544
    float* zq   = out + MROWS;               // 401408
    float* loss = out + MROWS + ZQ_ELEMS;    // 1

    float* ws   = (float*)d_ws;
    float* H    = ws;                         // 12544*768
    float* Zb   = H + (size_t)MROWS * KDIM;   // 12544*32
    float* EM   = Zb + (size_t)MROWS * EMB;   // 8192*32
    float* N2   = EM + (size_t)NCODE * EMB;   // 8192
    float* PART = N2 + NCODE;                 // 64
    // H is dead after K2 -> reuse its space for the per-split argmin pairs
    float* PMINV = H;                         // 12544*4
    float* PMINI = H + (size_t)MROWS * 4;     // 12544*4

    k0_norm_codebook<<<NCODE / 8, 256, 0, stream>>>(cb, EM, N2);
    k1_gemm_tanh<<<dim3(MROWS / BM1, KDIM / BN1), 128, 0, stream>>>(features, w1, b1, H);
    k2_gemm_norm<<<MROWS / 32, 256, 0, stream>>>(H, w2, b2, Zb);
    k3_argmin_part<<<dim3(MROWS / 64, 4), 256, 0, stream>>>(Zb, EM, N2, PMINV, PMINI);
    k3b_merge<<<MROWS / 256, 256, 0, stream>>>(Zb, EM, PMINV, PMINI, tok, zq, PART);
    k4_loss<<<1, 64, 0, stream>>>(PART, loss);
}

// Round 8
// 533.199 us; speedup vs baseline: 7.0338x; 4.6199x over previous
//
#include <hip/hip_runtime.h>
#include <math.h>

#define MROWS 12544        // B*N = 64*196
#define KDIM  768
#define EMB   32
#define NCODE 8192
#define ZQ_ELEMS 401408    // 64*32*14*14

// ---------------------------------------------------------------------------
// K0: normalize codebook rows; also store ||e||^2 (post-normalization, as ref)
// ---------------------------------------------------------------------------
__global__ __launch_bounds__(256) void k0_norm_codebook(
    const float* __restrict__ cb, float* __restrict__ em, float* __restrict__ n2)
{
    const int t = threadIdx.x;
    const int c = t & 31;
    const int r = blockIdx.x * 8 + (t >> 5);
    float v = cb[r * 32 + c];
    float s = v * v;
    #pragma unroll
    for (int off = 16; off; off >>= 1) s += __shfl_xor(s, off, 32);
    float e = v / sqrtf(s + 1e-12f);
    em[r * 32 + c] = e;
    float s2 = e * e;
    #pragma unroll
    for (int off = 16; off; off >>= 1) s2 += __shfl_xor(s2, off, 32);
    if (c == 0) n2[r] = s2;
}

// ---------------------------------------------------------------------------
// K1: H = tanh(X @ W1^T + b1).  64x192 tile, BK=16, 128 threads, 8x12
// microtile (strided frags: rows {tr*4, 32+tr*4}, cols tc*4+{0,64,128}).
//  - LDS-ratio: 96 FMA per 5 ds_read_b128 = 19.2:1 -> VALU-bound
//    (R4's 4x8 was 10.7:1 -> 62% VALUBusy ceiling).
//  - Grid (196,4)=784 <= 1024 resident (4 x 2-wave blocks/CU @ VGPR<=256)
//    -> single dispatch round (R4's 1176 grid had a 15% tail round).
//  - __launch_bounds__(128) ONE arg: two-arg forced VGPR=64+spill (R3,R6);
//    NO bounds also forced VGPR=64 (R7, default flat-wg-size=1024).
//  - All LDS access patterns <=2-way (free).
// ---------------------------------------------------------------------------
#define BM1 64
#define BN1 192
#define BK1 16

__global__ __launch_bounds__(128) void k1_gemm_tanh(
    const float* __restrict__ A, const float* __restrict__ W,
    const float* __restrict__ bias, float* __restrict__ H)
{
    __shared__ __align__(16) float As[2][BK1][64];
    __shared__ __align__(16) float Bs[2][BK1][192];

    const int t    = threadIdx.x;      // 0..127
    const int row0 = blockIdx.x * BM1;
    const int col0 = blockIdx.y * BN1;
    const int tc   = t & 15;           // cols tc*4 + {0,64,128}
    const int tr   = t >> 4;           // 0..7: rows tr*4+i and 32+tr*4+i

    const int arow = t & 63;           // A stage: row arow, k akq..akq+7
    const int akq  = (t >> 6) * 8;
    const int c2   = 128 + (t >> 1);   // B stage part2: col c2, k kq2..kq2+7
    const int kq2  = (t & 1) * 8;

    const float* Ap  = A + (size_t)(row0 + arow) * KDIM + akq;
    const float* Bp1 = W + (size_t)(col0 + t) * KDIM;         // part1: col t, k 0..15
    const float* Bp2 = W + (size_t)(col0 + c2) * KDIM + kq2;  // part2

    float acc[8][12];
    #pragma unroll
    for (int i = 0; i < 8; ++i)
        #pragma unroll
        for (int j = 0; j < 12; ++j) acc[i][j] = 0.f;

    // preload tile 0 (transposed into LDS; all writes <=2-way)
    {
        float4 a0 = *(const float4*)(Ap);
        float4 a1 = *(const float4*)(Ap + 4);
        float4 p0 = *(const float4*)(Bp1);
        float4 p1 = *(const float4*)(Bp1 + 4);
        float4 p2 = *(const float4*)(Bp1 + 8);
        float4 p3 = *(const float4*)(Bp1 + 12);
        float4 q0 = *(const float4*)(Bp2);
        float4 q1 = *(const float4*)(Bp2 + 4);
        As[0][akq+0][arow] = a0.x; As[0][akq+1][arow] = a0.y; As[0][akq+2][arow] = a0.z; As[0][akq+3][arow] = a0.w;
        As[0][akq+4][arow] = a1.x; As[0][akq+5][arow] = a1.y; As[0][akq+6][arow] = a1.z; As[0][akq+7][arow] = a1.w;
        Bs[0][0][t]  = p0.x; Bs[0][1][t]  = p0.y; Bs[0][2][t]  = p0.z; Bs[0][3][t]  = p0.w;
        Bs[0][4][t]  = p1.x; Bs[0][5][t]  = p1.y; Bs[0][6][t]  = p1.z; Bs[0][7][t]  = p1.w;
        Bs[0][8][t]  = p2.x; Bs[0][9][t]  = p2.y; Bs[0][10][t] = p2.z; Bs[0][11][t] = p2.w;
        Bs[0][12][t] = p3.x; Bs[0][13][t] = p3.y; Bs[0][14][t] = p3.z; Bs[0][15][t] = p3.w;
        Bs[0][kq2+0][c2] = q0.x; Bs[0][kq2+1][c2] = q0.y; Bs[0][kq2+2][c2] = q0.z; Bs[0][kq2+3][c2] = q0.w;
        Bs[0][kq2+4][c2] = q1.x; Bs[0][kq2+5][c2] = q1.y; Bs[0][kq2+6][c2] = q1.z; Bs[0][kq2+7][c2] = q1.w;
    }
    __syncthreads();

    const int nkt = KDIM / BK1;   // 48
    int buf = 0;
    for (int kt = 0; kt < nkt; ++kt) {
        float4 na0, na1, np0, np1, np2, np3, nq0, nq1;
        const bool pf = (kt + 1 < nkt);
        if (pf) {
            const int ko = (kt + 1) * BK1;
            na0 = *(const float4*)(Ap + ko);
            na1 = *(const float4*)(Ap + ko + 4);
            np0 = *(const float4*)(Bp1 + ko);
            np1 = *(const float4*)(Bp1 + ko + 4);
            np2 = *(const float4*)(Bp1 + ko + 8);
            np3 = *(const float4*)(Bp1 + ko + 12);
            nq0 = *(const float4*)(Bp2 + ko);
            nq1 = *(const float4*)(Bp2 + ko + 4);
        }
        #pragma unroll
        for (int k = 0; k < BK1; ++k) {
            float4 a0 = *(const float4*)&As[buf][k][tr * 4];
            float4 a1 = *(const float4*)&As[buf][k][32 + tr * 4];
            float4 b0 = *(const float4*)&Bs[buf][k][tc * 4];
            float4 b1 = *(const float4*)&Bs[buf][k][64 + tc * 4];
            float4 b2 = *(const float4*)&Bs[buf][k][128 + tc * 4];
            float a_[8]  = {a0.x, a0.y, a0.z, a0.w, a1.x, a1.y, a1.z, a1.w};
            float b_[12] = {b0.x, b0.y, b0.z, b0.w, b1.x, b1.y, b1.z, b1.w,
                            b2.x, b2.y, b2.z, b2.w};
            #pragma unroll
            for (int i = 0; i < 8; ++i)
                #pragma unroll
                for (int j = 0; j < 12; ++j)
                    acc[i][j] = fmaf(a_[i], b_[j], acc[i][j]);
        }
        if (pf) {
            const int nb = buf ^ 1;
            As[nb][akq+0][arow] = na0.x; As[nb][akq+1][arow] = na0.y; As[nb][akq+2][arow] = na0.z; As[nb][akq+3][arow] = na0.w;
            As[nb][akq+4][arow] = na1.x; As[nb][akq+5][arow] = na1.y; As[nb][akq+6][arow] = na1.z; As[nb][akq+7][arow] = na1.w;
            Bs[nb][0][t]  = np0.x; Bs[nb][1][t]  = np0.y; Bs[nb][2][t]  = np0.z; Bs[nb][3][t]  = np0.w;
            Bs[nb][4][t]  = np1.x; Bs[nb][5][t]  = np1.y; Bs[nb][6][t]  = np1.z; Bs[nb][7][t]  = np1.w;
            Bs[nb][8][t]  = np2.x; Bs[nb][9][t]  = np2.y; Bs[nb][10][t] = np2.z; Bs[nb][11][t] = np2.w;
            Bs[nb][12][t] = np3.x; Bs[nb][13][t] = np3.y; Bs[nb][14][t] = np3.z; Bs[nb][15][t] = np3.w;
            Bs[nb][kq2+0][c2] = nq0.x; Bs[nb][kq2+1][c2] = nq0.y; Bs[nb][kq2+2][c2] = nq0.z; Bs[nb][kq2+3][c2] = nq0.w;
            Bs[nb][kq2+4][c2] = nq1.x; Bs[nb][kq2+5][c2] = nq1.y; Bs[nb][kq2+6][c2] = nq1.z; Bs[nb][kq2+7][c2] = nq1.w;
        }
        __syncthreads();
        buf ^= 1;
    }

    float4 bc0 = *(const float4*)&bias[col0 + tc * 4];
    float4 bc1 = *(const float4*)&bias[col0 + 64 + tc * 4];
    float4 bc2 = *(const float4*)&bias[col0 + 128 + tc * 4];
    #pragma unroll
    for (int i = 0; i < 8; ++i) {
        const int row = row0 + ((i < 4) ? (tr * 4 + i) : (32 + tr * 4 + i - 4));
        float o0  = tanhf(acc[i][0]  + bc0.x);
        float o1  = tanhf(acc[i][1]  + bc0.y);
        float o2  = tanhf(acc[i][2]  + bc0.z);
        float o3  = tanhf(acc[i][3]  + bc0.w);
        float o4  = tanhf(acc[i][4]  + bc1.x);
        float o5  = tanhf(acc[i][5]  + bc1.y);
        float o6  = tanhf(acc[i][6]  + bc1.z);
        float o7  = tanhf(acc[i][7]  + bc1.w);
        float o8  = tanhf(acc[i][8]  + bc2.x);
        float o9  = tanhf(acc[i][9]  + bc2.y);
        float o10 = tanhf(acc[i][10] + bc2.z);
        float o11 = tanhf(acc[i][11] + bc2.w);
        *(float4*)&H[(size_t)row * KDIM + col0 + tc * 4]       = make_float4(o0, o1, o2, o3);
        *(float4*)&H[(size_t)row * KDIM + col0 + 64 + tc * 4]  = make_float4(o4, o5, o6, o7);
        *(float4*)&H[(size_t)row * KDIM + col0 + 128 + tc * 4] = make_float4(o8, o9, o10, o11);
    }
}

// ---------------------------------------------------------------------------
// K2: Z = l2norm(H @ W2^T + b2).  32 rows/block -> 392 blocks.
// ---------------------------------------------------------------------------
#define K2C 64
__global__ __launch_bounds__(256) void k2_gemm_norm(
    const float* __restrict__ H, const float* __restrict__ W2,
    const float* __restrict__ b2, float* __restrict__ Z)
{
    __shared__ __align__(16) float As2[32][68];
    __shared__ __align__(16) float Ws2[32][68];

    const int t    = threadIdx.x;
    const int row0 = blockIdx.x * 32;
    const int cg   = t & 7;
    const int rg   = t >> 3;

    float acc[4] = {0.f, 0.f, 0.f, 0.f};

    for (int kc = 0; kc < KDIM; kc += K2C) {
        __syncthreads();
        {
            const int r = t >> 3, kq = (t & 7) * 8;
            *(float4*)&As2[r][kq]     = *(const float4*)&H[(size_t)(row0 + r) * KDIM + kc + kq];
            *(float4*)&As2[r][kq + 4] = *(const float4*)&H[(size_t)(row0 + r) * KDIM + kc + kq + 4];
            *(float4*)&Ws2[r][kq]     = *(const float4*)&W2[(size_t)r * KDIM + kc + kq];
            *(float4*)&Ws2[r][kq + 4] = *(const float4*)&W2[(size_t)r * KDIM + kc + kq + 4];
        }
        __syncthreads();
        #pragma unroll
        for (int k4 = 0; k4 < K2C / 4; ++k4) {
            float4 a4 = *(const float4*)&As2[rg][k4 * 4];
            #pragma unroll
            for (int c = 0; c < 4; ++c) {
                float4 w4 = *(const float4*)&Ws2[cg * 4 + c][k4 * 4];
                acc[c] = fmaf(a4.x, w4.x, acc[c]);
                acc[c] = fmaf(a4.y, w4.y, acc[c]);
                acc[c] = fmaf(a4.z, w4.z, acc[c]);
                acc[c] = fmaf(a4.w, w4.w, acc[c]);
            }
        }
    }

    float h0 = acc[0] + b2[cg * 4 + 0];
    float h1 = acc[1] + b2[cg * 4 + 1];
    float h2 = acc[2] + b2[cg * 4 + 2];
    float h3 = acc[3] + b2[cg * 4 + 3];
    float s = h0*h0 + h1*h1 + h2*h2 + h3*h3;
    #pragma unroll
    for (int off = 1; off < 8; off <<= 1) s += __shfl_xor(s, off, 8);
    const float den = sqrtf(s + 1e-12f);
    const int r = row0 + rg;
    *(float4*)&Z[(size_t)r * EMB + cg * 4] = make_float4(h0/den, h1/den, h2/den, h3/den);
}

// ---------------------------------------------------------------------------
// K3: per (64-row block, 2048-code split) partial argmin of ||e||^2 - 2 z.e
// Grid (196, 4) = 784 blocks. Single-buffered staging. LDS 27.5KB.
// ---------------------------------------------------------------------------
__global__ __launch_bounds__(256) void k3_argmin_part(
    const float* __restrict__ Z, const float* __restrict__ EM,
    const float* __restrict__ N2, float* __restrict__ pminv,
    float* __restrict__ pmini)
{
    __shared__ __align__(16) float Zs[64][36];
    __shared__ __align__(16) float Es[128][36];
    __shared__ float Ns[128];

    const int t     = threadIdx.x;
    const int row0  = blockIdx.x * 64;
    const int cbase = blockIdx.y * 2048;
    const int cg    = t & 15;
    const int rg    = t >> 4;

    #pragma unroll
    for (int i = 0; i < 2; ++i) {
        const int fi = t + 256 * i;
        const int r = fi >> 3, kq = fi & 7;
        *(float4*)&Zs[r][kq * 4] = *(const float4*)&Z[(size_t)(row0 + r) * EMB + kq * 4];
    }

    float minv[4] = {INFINITY, INFINITY, INFINITY, INFINITY};
    int   mini[4] = {0, 0, 0, 0};

    for (int tile = 0; tile < 16; ++tile) {
        __syncthreads();
        const int tb = cbase + tile * 128;
        #pragma unroll
        for (int i = 0; i < 4; ++i) {
            const int fi = t + 256 * i;
            const int c = fi >> 3, kq = fi & 7;
            *(float4*)&Es[c][kq * 4] = *(const float4*)&EM[(size_t)(tb + c) * EMB + kq * 4];
        }
        if (t < 128) Ns[t] = N2[tb + t];
        __syncthreads();

        float dot[4][8];
        #pragma unroll
        for (int rr = 0; rr < 4; ++rr)
            #pragma unroll
            for (int cc = 0; cc < 8; ++cc) dot[rr][cc] = 0.f;

        #pragma unroll
        for (int k4 = 0; k4 < 8; ++k4) {
            float4 z4[4];
            #pragma unroll
            for (int rr = 0; rr < 4; ++rr) z4[rr] = *(const float4*)&Zs[rg + 16 * rr][k4 * 4];
            #pragma unroll
            for (int cc = 0; cc < 8; ++cc) {
                float4 e4 = *(const float4*)&Es[cg + 16 * cc][k4 * 4];
                #pragma unroll
                for (int rr = 0; rr < 4; ++rr) {
                    dot[rr][cc] = fmaf(z4[rr].x, e4.x, dot[rr][cc]);
                    dot[rr][cc] = fmaf(z4[rr].y, e4.y, dot[rr][cc]);
                    dot[rr][cc] = fmaf(z4[rr].z, e4.z, dot[rr][cc]);
                    dot[rr][cc] = fmaf(z4[rr].w, e4.w, dot[rr][cc]);
                }
            }
        }
        #pragma unroll
        for (int cc = 0; cc < 8; ++cc) {
            const int cl = cg + 16 * cc;
            const float n2v = Ns[cl];
            const int gi = tb + cl;
            #pragma unroll
            for (int rr = 0; rr < 4; ++rr) {
                const float sc = fmaf(-2.f, dot[rr][cc], n2v);
                if (sc < minv[rr]) { minv[rr] = sc; mini[rr] = gi; }
            }
        }
    }

    // reduce across 16 code-group lanes per row; ties -> smaller index
    #pragma unroll
    for (int rr = 0; rr < 4; ++rr) {
        #pragma unroll
        for (int off = 8; off; off >>= 1) {
            const float ov = __shfl_xor(minv[rr], off, 16);
            const int   oi = __shfl_xor(mini[rr], off, 16);
            if (ov < minv[rr] || (ov == minv[rr] && oi < mini[rr])) {
                minv[rr] = ov; mini[rr] = oi;
            }
        }
        if (cg == 0) {
            const int row = row0 + rg + 16 * rr;
            pminv[row * 4 + blockIdx.y] = minv[rr];
            pmini[row * 4 + blockIdx.y] = (float)mini[rr];
        }
    }
}

// ---------------------------------------------------------------------------
// K3b: merge 4 splits per row; write token, z_q (B,32,14,14), loss partials.
// ---------------------------------------------------------------------------
__global__ __launch_bounds__(256) void k3b_merge(
    const float* __restrict__ Z, const float* __restrict__ EM,
    const float* __restrict__ pminv, const float* __restrict__ pmini,
    float* __restrict__ tok, float* __restrict__ zq, float* __restrict__ part)
{
    const int t = threadIdx.x;
    const int row = blockIdx.x * 256 + t;

    float4 mv = *(const float4*)&pminv[row * 4];
    float4 mi = *(const float4*)&pmini[row * 4];
    float best = mv.x; int bi = (int)mi.x;
    if (mv.y < best) { best = mv.y; bi = (int)mi.y; }
    if (mv.z < best) { best = mv.z; bi = (int)mi.z; }
    if (mv.w < best) { best = mv.w; bi = (int)mi.w; }
    tok[row] = (float)bi;

    const int b = row / 196, n = row % 196;
    float lp = 0.f;
    #pragma unroll
    for (int q = 0; q < 8; ++q) {
        float4 e = *(const float4*)&EM[(size_t)bi * EMB + q * 4];
        float4 z = *(const float4*)&Z[(size_t)row * EMB + q * 4];
        float d0 = e.x - z.x, d1 = e.y - z.y, d2 = e.z - z.z, d3 = e.w - z.w;
        lp = fmaf(d0, d0, lp); lp = fmaf(d1, d1, lp);
        lp = fmaf(d2, d2, lp); lp = fmaf(d3, d3, lp);
        const size_t zb = (size_t)b * 6272 + n;
        zq[zb + (q * 4 + 0) * 196] = e.x;
        zq[zb + (q * 4 + 1) * 196] = e.y;
        zq[zb + (q * 4 + 2) * 196] = e.z;
        zq[zb + (q * 4 + 3) * 196] = e.w;
    }
    #pragma unroll
    for (int off = 32; off; off >>= 1) lp += __shfl_xor(lp, off, 64);
    __shared__ float r4[4];
    if ((t & 63) == 0) r4[t >> 6] = lp;
    __syncthreads();
    if (t == 0) part[blockIdx.x] = r4[0] + r4[1] + r4[2] + r4[3];
}

// ---------------------------------------------------------------------------
// K4: deterministic loss reduce over 49 partials
// ---------------------------------------------------------------------------
__global__ __launch_bounds__(64) void k4_loss(
    const float* __restrict__ part, float* __restrict__ loss)
{
    const int t = threadIdx.x;
    float v = (t < 49) ? part[t] : 0.f;
    #pragma unroll
    for (int off = 32; off; off >>= 1) v += __shfl_xor(v, off, 64);
    if (t == 0) loss[0] = v * (1.0f / 401408.f);
}

// ---------------------------------------------------------------------------
extern "C" void kernel_launch(void* const* d_in, const int* in_sizes, int n_in,
                              void* d_out, int out_size, void* d_ws, size_t ws_size,
                              hipStream_t stream)
{
    (void)in_sizes; (void)n_in; (void)out_size; (void)ws_size;
    const float* features = (const float*)d_in[0];
    const float* w1 = (const float*)d_in[1];
    const float* b1 = (const float*)d_in[2];
    const float* w2 = (const float*)d_in[3];
    const float* b2 = (const float*)d_in[4];
    const float* cb = (const float*)d_in[5];

    float* out  = (float*)d_out;
    float* tok  = out;                       // 12544
    float* zq   = out + MROWS;               // 401408
    float* loss = out + MROWS + ZQ_ELEMS;    // 1

    float* ws   = (float*)d_ws;
    float* H    = ws;                         // 12544*768
    float* Zb   = H + (size_t)MROWS * KDIM;   // 12544*32
    float* EM   = Zb + (size_t)MROWS * EMB;   // 8192*32
    float* N2   = EM + (size_t)NCODE * EMB;   // 8192
    float* PART = N2 + NCODE;                 // 64
    // H is dead after K2 -> reuse its space for the per-split argmin pairs
    float* PMINV = H;                         // 12544*4
    float* PMINI = H + (size_t)MROWS * 4;     // 12544*4

    k0_norm_codebook<<<NCODE / 8, 256, 0, stream>>>(cb, EM, N2);
    k1_gemm_tanh<<<dim3(MROWS / BM1, KDIM / BN1), 128, 0, stream>>>(features, w1, b1, H);
    k2_gemm_norm<<<MROWS / 32, 256, 0, stream>>>(H, w2, b2, Zb);
    k3_argmin_part<<<dim3(MROWS / 64, 4), 256, 0, stream>>>(Zb, EM, N2, PMINV, PMINI);
    k3b_merge<<<MROWS / 256, 256, 0, stream>>>(Zb, EM, PMINV, PMINI, tok, zq, PART);
    k4_loss<<<1, 64, 0, stream>>>(PART, loss);
}